// Round 8
// baseline (362.943 us; speedup 1.0000x reference)
//
#include <hip/hip_runtime.h>

// AttentionXL (TransformerXL relative attention), MI355X gfx950.
// fp32 I/O. convert3 + transpose4 -> kv GEMM (epilogue emits Kt + vtmp) ->
// q GEMM -> r GEMM (epilogue emits Rt) -> V repack (Vt) -> barrier-free
// 1-wave-per-block flash (all fragments = dense coalesced global loads from
// compact per-(b,h) layouts; rel-shift gather via quad-local shuffles) ->
// proj GEMM.

typedef unsigned short u16;
typedef short short8 __attribute__((ext_vector_type(8)));
typedef float f32x4 __attribute__((ext_vector_type(4)));

#define BSZ 4
#define PREV 512

__device__ __forceinline__ float b2f(u16 u) {
  union { unsigned int i; float f; } x; x.i = ((unsigned int)u) << 16; return x.f;
}
__device__ __forceinline__ u16 f2b(float f) {
  union { float f; unsigned int i; } x; x.f = f;
  unsigned int u = x.i;
  return (u16)((u + 0x7fffu + ((u >> 16) & 1u)) >> 16);
}
__device__ __forceinline__ void storeC(u16* C, size_t idx, float v) { C[idx] = f2b(v); }
__device__ __forceinline__ void storeC(float* C, size_t idx, float v) { C[idx] = v; }

// ---------------------------------------------------------------------------
// 3 fp32->bf16 flat converts in one dispatch (4M / 2M / 1M elements).
// ---------------------------------------------------------------------------
__global__ __launch_bounds__(256)
void convert3(const float* __restrict__ s0, const float* __restrict__ s1,
              const float* __restrict__ s2, u16* __restrict__ d0,
              u16* __restrict__ d1, u16* __restrict__ d2) {
  int bx = blockIdx.x;
  const float* s; u16* d; size_t base;
  if (bx < 2048)      { s = s0; d = d0; base = (size_t)bx * 2048; }
  else if (bx < 3072) { s = s1; d = d1; base = (size_t)(bx - 2048) * 2048; }
  else                { s = s2; d = d2; base = (size_t)(bx - 3072) * 2048; }
  size_t i = base + (size_t)threadIdx.x * 8;
  const f32x4* p = reinterpret_cast<const f32x4*>(s + i);
  f32x4 a = p[0], b = p[1];
  short8 r;
#pragma unroll
  for (int e = 0; e < 4; e++) { r[e] = (short)f2b(a[e]); r[e + 4] = (short)f2b(b[e]); }
  *reinterpret_cast<short8*>(d + i) = r;
}

// ---------------------------------------------------------------------------
// 4 weight transposes (fp32 W[K x N] -> bf16 WT[N x K]) in one dispatch.
// ---------------------------------------------------------------------------
__global__ __launch_bounds__(256)
void transpose4(const float* __restrict__ W0, const float* __restrict__ W1,
                const float* __restrict__ W2, const float* __restrict__ W3,
                u16* __restrict__ T0, u16* __restrict__ T1,
                u16* __restrict__ T2, u16* __restrict__ T3) {
  const int z = blockIdx.z;
  const float* W; u16* T; int N;
  if (z == 0)      { W = W0; T = T0; N = 2048; }
  else if (z == 1) { W = W1; T = T1; N = 1024; }
  else if (z == 2) { W = W2; T = T2; N = 1024; }
  else             { W = W3; T = T3; N = 1024; }
  const int K = 1024;
  const int n0 = blockIdx.x * 64, k0 = blockIdx.y * 64;
  if (n0 >= N) return;

  __shared__ u16 ld[64 * 66];
  const int tid = threadIdx.x;
#pragma unroll
  for (int rep = 0; rep < 16; rep++) {
    int idx = tid + 256 * rep;
    int kk = idx >> 6, nn = idx & 63;
    ld[kk * 66 + nn] = f2b(W[(size_t)(k0 + kk) * N + n0 + nn]);
  }
  __syncthreads();
#pragma unroll
  for (int rep = 0; rep < 16; rep++) {
    int idx = tid + 256 * rep;
    int nn = idx >> 6, kk = idx & 63;
    T[(size_t)(n0 + nn) * K + k0 + kk] = ld[kk * 66 + nn];
  }
}

// ---------------------------------------------------------------------------
// V repack: vtmp[(j*4+b)][h*64+d] -> Vt[b][h][d][j]. 64x64 tiles via LDS.
// grid = (16 j-chunks, 4 b, 16 h).
// ---------------------------------------------------------------------------
__global__ __launch_bounds__(256)
void vtrans(const u16* __restrict__ vtmp, u16* __restrict__ Vt) {
  const int jc = blockIdx.x, b = blockIdx.y, h = blockIdx.z;
  __shared__ u16 ld[64 * 66];
  const int tid = threadIdx.x;
#pragma unroll
  for (int rep = 0; rep < 16; rep++) {
    int idx = tid + 256 * rep;
    int jj = idx >> 6, dd = idx & 63;
    ld[jj * 66 + dd] = vtmp[(size_t)((jc * 64 + jj) * 4 + b) * 1024 + h * 64 + dd];
  }
  __syncthreads();
#pragma unroll
  for (int rep = 0; rep < 16; rep++) {
    int idx = tid + 256 * rep;
    int dd = idx >> 6, jj = idx & 63;
    Vt[(((size_t)b * 16 + h) * 64 + dd) * 1024 + jc * 64 + jj] = ld[jj * 66 + dd];
  }
}

// ---------------------------------------------------------------------------
// GEMM (B^T form): C = A[M,K] @ BT[N,K]^T + bias. 128x128 tile, BK=64.
// MODE 0: row-major C. MODE 1 (kv): cols<1024 -> Kt[b][h][j][d], else vtmp
// row-major. MODE 2 (r): C -> Rt[h][rel][d].
// ---------------------------------------------------------------------------
template <typename OT, int MODE>
__global__ __launch_bounds__(256, 2)
void gemm_bt(const u16* __restrict__ A, const u16* __restrict__ BT,
             const float* __restrict__ bias, OT* __restrict__ C,
             u16* __restrict__ C2, int M, int N, int K)
{
  __shared__ __align__(16) short at[8192];
  __shared__ __align__(16) short bt[8192];

  const int tid = threadIdx.x;
  const int lane = tid & 63, w = tid >> 6;
  const int wr = w >> 1, wc = w & 1;
  const int quad = lane >> 4, ml = lane & 15;
  const int row0 = blockIdx.y * 128, col0 = blockIdx.x * 128;

  f32x4 acc[4][4];
  const f32x4 fzero = {0.f, 0.f, 0.f, 0.f};
#pragma unroll
  for (int i = 0; i < 4; i++)
#pragma unroll
    for (int j = 0; j < 4; j++) acc[i][j] = fzero;

  for (int k0 = 0; k0 < K; k0 += 64) {
    __syncthreads();
#pragma unroll
    for (int cc = 0; cc < 4; cc++) {
      int c = tid + 256 * cc;
      int m = c >> 3, oct = c & 7;
      short8 val = *reinterpret_cast<const short8*>(A + (size_t)(row0 + m) * K + k0 + oct * 8);
      int mc = m >> 4, mll = m & 15, kc = oct >> 2, qd = oct & 3;
      *reinterpret_cast<short8*>(at + (((mc * 2 + kc) * 64) + qd * 16 + mll) * 8) = val;
    }
#pragma unroll
    for (int cc = 0; cc < 4; cc++) {
      int c = tid + 256 * cc;
      int n = c >> 3, oct = c & 7;
      short8 val = *reinterpret_cast<const short8*>(BT + (size_t)(col0 + n) * K + k0 + oct * 8);
      int nc = n >> 4, nl = n & 15, kc = oct >> 2, qd = oct & 3;
      *reinterpret_cast<short8*>(bt + (((nc * 2 + kc) * 64) + qd * 16 + nl) * 8) = val;
    }
    __syncthreads();

    short8 af[4][2], bf[4][2];
#pragma unroll
    for (int mc = 0; mc < 4; mc++)
#pragma unroll
      for (int kc = 0; kc < 2; kc++)
        af[mc][kc] = *reinterpret_cast<const short8*>(at + ((((wr * 4 + mc) * 2 + kc) * 64) + lane) * 8);
#pragma unroll
    for (int nc = 0; nc < 4; nc++)
#pragma unroll
      for (int kc = 0; kc < 2; kc++)
        bf[nc][kc] = *reinterpret_cast<const short8*>(bt + ((((wc * 4 + nc) * 2 + kc) * 64) + lane) * 8);

#pragma unroll
    for (int mc = 0; mc < 4; mc++)
#pragma unroll
      for (int nc = 0; nc < 4; nc++)
#pragma unroll
        for (int kc = 0; kc < 2; kc++)
          acc[mc][nc] = __builtin_amdgcn_mfma_f32_16x16x32_bf16(af[mc][kc], bf[nc][kc], acc[mc][nc], 0, 0, 0);
  }

#pragma unroll
  for (int nc = 0; nc < 4; nc++) {
    int col = col0 + wc * 64 + nc * 16 + ml;
    float bv = bias[col];
#pragma unroll
    for (int mc = 0; mc < 4; mc++) {
#pragma unroll
      for (int reg = 0; reg < 4; reg++) {
        int row = row0 + wr * 64 + mc * 16 + quad * 4 + reg;
        float val = acc[mc][nc][reg] + bv;
        if constexpr (MODE == 0) {
          storeC(C, (size_t)row * N + col, val);
        } else if constexpr (MODE == 1) {
          if (col < 1024) {  // K half -> Kt[b][h][j][d]
            int h = col >> 6, d = col & 63, j = row >> 2, bb = row & 3;
            C[(((size_t)bb * 16 + h) * 1024 + j) * 64 + d] = f2b(val);
          } else {           // V half -> vtmp row-major
            C2[(size_t)row * 1024 + (col - 1024)] = f2b(val);
          }
        } else {             // MODE 2: Rt[h][rel][d]
          int h = col >> 6, d = col & 63;
          C[(((size_t)h) * 1024 + row) * 64 + d] = f2b(val);
        }
      }
    }
  }
}

// ---------------------------------------------------------------------------
// Barrier-free fused flash-XL: one wave (64-thread block) per (16 q-rows,
// b, h). All K/R/V fragments are direct global 16B/lane loads from compact
// layouts (each instruction covers a dense 1KB window). Rel-shift gather via
// quad-local shuffles (source register is nc or nc+1; lane = quad*16 +
// ((ml-rowl-1)&15)). Scale 1/8 folded into Q fragments. LDS: only the 2KB
// per-wave P transpose (wave-order safe, no __syncthreads anywhere).
// ---------------------------------------------------------------------------
__global__ __launch_bounds__(64, 2)
void flash_xl(const u16* __restrict__ q, const u16* __restrict__ Kt,
              const u16* __restrict__ Vt, const u16* __restrict__ Rt,
              const float* __restrict__ u, const float* __restrict__ v,
              u16* __restrict__ av)
{
  __shared__ __align__(16) short pt[1024];

  const int lane = threadIdx.x;
  const int quad = lane >> 4, ml = lane & 15;
  const int ic = 31 - blockIdx.x;  // longest blocks (most j-tiles) first
  const int b = blockIdx.y, h = blockIdx.z;
  const int ig0 = ic * 16;

  const u16* Kp = Kt + ((size_t)b * 16 + h) * 1024 * 64;
  const u16* Vp = Vt + ((size_t)b * 16 + h) * 64 * 1024;
  const u16* Rp = Rt + (size_t)h * 1024 * 64;

  // Q fragments, pre-scaled by 1/8: rows ig0+ml, k = kc*32+quad*8+e
  short8 qu[2], qvf[2];
  {
    int ig = ig0 + ml;
#pragma unroll
    for (int kc = 0; kc < 2; kc++) {
      int dbase = kc * 32 + quad * 8;
      short8 qq = *reinterpret_cast<const short8*>(q + ((size_t)ig * BSZ + b) * 1024 + h * 64 + dbase);
      const f32x4* up = reinterpret_cast<const f32x4*>(u + h * 64 + dbase);
      const f32x4* vp = reinterpret_cast<const f32x4*>(v + h * 64 + dbase);
      f32x4 u0 = up[0], u1 = up[1], v0 = vp[0], v1 = vp[1];
#pragma unroll
      for (int e = 0; e < 8; e++) {
        float qf = b2f((u16)qq[e]);
        float uu = (e < 4) ? u0[e] : u1[e - 4];
        float vv = (e < 4) ? v0[e] : v1[e - 4];
        qu[kc][e]  = (short)f2b((qf + uu) * 0.125f);
        qvf[kc][e] = (short)f2b((qf + vv) * 0.125f);
      }
    }
  }

  const f32x4 fzero = {0.f, 0.f, 0.f, 0.f};
  f32x4 o_acc[4];
#pragma unroll
  for (int i = 0; i < 4; i++) o_acc[i] = fzero;
  float m_run[4], l_run[4];
#pragma unroll
  for (int i = 0; i < 4; i++) { m_run[i] = -1e30f; l_run[i] = 0.f; }

  const int ntiles = ((ig0 + 527) >> 6) + 1;  // covers j <= ig0+15+512
  for (int t = 0; t < ntiles; t++) {
    const int j0 = t * 64;
    const int relstart = j0 - ig0 + 496;           // rel = relstart + rrw
    const bool masked = (j0 + 63) > (ig0 + PREV);  // any masked entry?

    // ---- content scores: K B-frag direct loads (dense 1KB/instr)
    f32x4 sc[4];
#pragma unroll
    for (int nc = 0; nc < 4; nc++) {
      sc[nc] = fzero;
      const u16* kp = Kp + (size_t)(j0 + nc * 16 + ml) * 64 + quad * 8;
#pragma unroll
      for (int kc = 0; kc < 2; kc++) {
        short8 kf = *reinterpret_cast<const short8*>(kp + kc * 32);
        sc[nc] = __builtin_amdgcn_mfma_f32_16x16x32_bf16(qu[kc], kf, sc[nc], 0, 0, 0);
      }
    }
    // ---- position strip pos2[16 rows][80 cols]: R B-frag direct loads
    f32x4 p2[5];
#pragma unroll
    for (int c = 0; c < 5; c++) {
      p2[c] = fzero;
      int rel = relstart + c * 16 + ml;
      if (rel > 1023) rel = 1023;  // clamped rows are masked below
      const u16* rp = Rp + (size_t)rel * 64 + quad * 8;
#pragma unroll
      for (int kc = 0; kc < 2; kc++) {
        short8 rf = *reinterpret_cast<const short8*>(rp + kc * 32);
        p2[c] = __builtin_amdgcn_mfma_f32_16x16x32_bf16(qvf[kc], rf, p2[c], 0, 0, 0);
      }
    }

    // ---- rel-shift gather (quad-local shuffles) + mask + online softmax
    float pv_[4][4];
    float tmax[4] = {-1e30f, -1e30f, -1e30f, -1e30f};
#pragma unroll
    for (int reg = 0; reg < 4; reg++) {
      int rowl = quad * 4 + reg;
      int src = quad * 16 + ((ml - rowl - 1) & 15);
      bool hi = ml > rowl;  // pos2 col rrw = nc*16 + (15+ml-rowl): chunk nc or nc+1
      float sh[5];
#pragma unroll
      for (int c = 0; c < 5; c++) sh[c] = __shfl(p2[c][reg], src, 64);
#pragma unroll
      for (int nc = 0; nc < 4; nc++) {
        float s = sc[nc][reg] + (hi ? sh[nc + 1] : sh[nc]);
        if (masked) {
          int jg = j0 + nc * 16 + ml;
          if (jg > ig0 + rowl + PREV) s = -1e30f;
        }
        pv_[nc][reg] = s;
        tmax[reg] = fmaxf(tmax[reg], s);
      }
    }
#pragma unroll
    for (int reg = 0; reg < 4; reg++) {
      float tm = tmax[reg];
#pragma unroll
      for (int off = 1; off < 16; off <<= 1) tm = fmaxf(tm, __shfl_xor(tm, off, 64));
      float mnew = fmaxf(m_run[reg], tm);
      float alpha = __expf(m_run[reg] - mnew);
      float rs = 0.f;
#pragma unroll
      for (int nc = 0; nc < 4; nc++) {
        float p = __expf(pv_[nc][reg] - mnew);
        pv_[nc][reg] = p;
        rs += p;
      }
#pragma unroll
      for (int off = 1; off < 16; off <<= 1) rs += __shfl_xor(rs, off, 64);
      l_run[reg] = l_run[reg] * alpha + rs;
      m_run[reg] = mnew;
#pragma unroll
      for (int nc = 0; nc < 4; nc++) o_acc[nc][reg] *= alpha;
    }

    // ---- P (C layout) -> bf16 A-frag via per-wave LDS (wave-order safe)
#pragma unroll
    for (int nc = 0; nc < 4; nc++) {
      int jl = nc * 16 + ml;
      int kc = nc >> 1, qdj = (jl >> 3) & 3, jj = ml & 7;
#pragma unroll
      for (int reg = 0; reg < 4; reg++) {
        int rowl = quad * 4 + reg;
        pt[(kc * 64 + qdj * 16 + rowl) * 8 + jj] = (short)f2b(pv_[nc][reg]);
      }
    }
    short8 pf[2];
    pf[0] = *reinterpret_cast<const short8*>(pt + (0 * 64 + lane) * 8);
    pf[1] = *reinterpret_cast<const short8*>(pt + (1 * 64 + lane) * 8);

    // ---- PV: V B-frag direct loads from Vt (dense 1KB/instr), k = jl
#pragma unroll
    for (int ncd = 0; ncd < 4; ncd++) {
      const u16* vp = Vp + (size_t)(ncd * 16 + ml) * 1024 + j0 + quad * 8;
#pragma unroll
      for (int kc = 0; kc < 2; kc++) {
        short8 vf = *reinterpret_cast<const short8*>(vp + kc * 32);
        o_acc[ncd] = __builtin_amdgcn_mfma_f32_16x16x32_bf16(pf[kc], vf, o_acc[ncd], 0, 0, 0);
      }
    }
  }

  // ---- normalize and write attn_vec
  float inv[4];
#pragma unroll
  for (int reg = 0; reg < 4; reg++) inv[reg] = 1.0f / l_run[reg];
#pragma unroll
  for (int ncd = 0; ncd < 4; ncd++) {
#pragma unroll
    for (int reg = 0; reg < 4; reg++) {
      int ig = ig0 + quad * 4 + reg;
      av[((size_t)ig * BSZ + b) * 1024 + h * 64 + ncd * 16 + ml] = f2b(o_acc[ncd][reg] * inv[reg]);
    }
  }
}

// ---------------------------------------------------------------------------
extern "C" void kernel_launch(void* const* d_in, const int* in_sizes, int n_in,
                              void* d_out, int out_size, void* d_ws, size_t ws_size,
                              hipStream_t stream) {
  (void)in_sizes; (void)n_in; (void)out_size; (void)ws_size;

  const float* inputs  = (const float*)d_in[0];   // (512,4,1024)
  const float* pos_emb = (const float*)d_in[1];   // (1024,1,1024)
  const float* full_in = (const float*)d_in[2];   // (1024,4,1024)
  const float* u       = (const float*)d_in[3];   // (16,64)
  const float* v       = (const float*)d_in[4];   // (16,64)
  const float* W_kv    = (const float*)d_in[5];   // (1024,2048)
  const float* b_kv    = (const float*)d_in[6];   // (2048,)
  const float* W_q     = (const float*)d_in[7];   // (1024,1024)
  const float* b_q     = (const float*)d_in[8];
  const float* W_pos   = (const float*)d_in[9];   // (1024,1024)
  const float* b_pos   = (const float*)d_in[10];
  const float* W_proj  = (const float*)d_in[11];  // (1024,1024)
  const float* b_proj  = (const float*)d_in[12];
  // d_in[13] = mask (bool) — recomputed analytically (j > i + 512)
  float* out = (float*)d_out;

  char* ws = (char*)d_ws;
  u16* Kt    = (u16*)(ws);                  //  8 MB: [4 b][16 h][1024 j][64 d]
  u16* vtmp  = (u16*)(ws + ( 8u << 20));    //  8 MB: [4096 (j,b)][1024 (h,d)]
  u16* Vt    = (u16*)(ws + (16u << 20));    //  8 MB: [4 b][16 h][64 d][1024 j]
  u16* qq    = (u16*)(ws + (24u << 20));    //  4 MB: 2048x1024
  u16* Rt    = (u16*)(ws + (28u << 20));    //  2 MB: [16 h][1024 rel][64 d]
  u16* av    = (u16*)(ws + (30u << 20));    //  4 MB: 2048x1024
  u16* fibf  = (u16*)(ws + (34u << 20));    //  8 MB: 4096x1024
  u16* inbf  = (u16*)(ws + (42u << 20));    //  4 MB: 2048x1024
  u16* pebf  = (u16*)(ws + (46u << 20));    //  2 MB: 1024x1024
  u16* WkvT  = (u16*)(ws + (48u << 20));    //  4 MB: 2048x1024
  u16* WqT   = (u16*)(ws + (52u << 20));    //  2 MB: 1024x1024
  u16* WposT = (u16*)(ws + (54u << 20));    //  2 MB: 1024x1024
  u16* WprojT= (u16*)(ws + (56u << 20));    //  2 MB: 1024x1024

  // --- precompute
  hipLaunchKernelGGL(convert3, dim3(3584), dim3(256), 0, stream,
                     full_in, inputs, pos_emb, fibf, inbf, pebf);
  hipLaunchKernelGGL(transpose4, dim3(32, 16, 4), dim3(256), 0, stream,
                     W_kv, W_q, W_pos, W_proj, WkvT, WqT, WposT, WprojT);

  // --- GEMMs
  hipLaunchKernelGGL((gemm_bt<u16, 1>), dim3(16, 32), dim3(256), 0, stream,
                     fibf, WkvT, b_kv, Kt, vtmp, 4096, 2048, 1024);
  hipLaunchKernelGGL((gemm_bt<u16, 0>), dim3(8, 16), dim3(256), 0, stream,
                     inbf, WqT, b_q, qq, (u16*)nullptr, 2048, 1024, 1024);
  hipLaunchKernelGGL((gemm_bt<u16, 2>), dim3(8, 8), dim3(256), 0, stream,
                     pebf, WposT, b_pos, Rt, (u16*)nullptr, 1024, 1024, 1024);
  // --- V repack
  hipLaunchKernelGGL(vtrans, dim3(16, 4, 16), dim3(256), 0, stream, vtmp, Vt);
  // --- fused attention (one wave per block)
  hipLaunchKernelGGL(flash_xl, dim3(32, 4, 16), dim3(64), 0, stream,
                     qq, Kt, Vt, Rt, u, v, av);
  // --- output projection
  hipLaunchKernelGGL((gemm_bt<float, 0>), dim3(8, 16), dim3(256), 0, stream,
                     av, WprojT, b_proj, out, (u16*)nullptr, 2048, 1024, 1024);
}

// Round 9
// 303.538 us; speedup vs baseline: 1.1957x; 1.1957x over previous
//
#include <hip/hip_runtime.h>

// AttentionXL (TransformerXL relative attention), MI355X gfx950.
// fp32 I/O. convert3 + transpose4 -> kv GEMM (epilogue emits Kt2/Vt2 in MFMA
// frag-tile order) -> q GEMM -> r GEMM (Rt[h][rel][d]) -> split-j flash
// (4-wave blocks, identity-copy LDS staging, shuffle rel-gather, 16 waves/CU)
// -> combine -> proj GEMM.

typedef unsigned short u16;
typedef short short8 __attribute__((ext_vector_type(8)));
typedef float f32x4 __attribute__((ext_vector_type(4)));

#define BSZ 4
#define PREV 512

__device__ __forceinline__ float b2f(u16 u) {
  union { unsigned int i; float f; } x; x.i = ((unsigned int)u) << 16; return x.f;
}
__device__ __forceinline__ u16 f2b(float f) {
  union { float f; unsigned int i; } x; x.f = f;
  unsigned int u = x.i;
  return (u16)((u + 0x7fffu + ((u >> 16) & 1u)) >> 16);
}
__device__ __forceinline__ void storeC(u16* C, size_t idx, float v) { C[idx] = f2b(v); }
__device__ __forceinline__ void storeC(float* C, size_t idx, float v) { C[idx] = v; }

// ---------------------------------------------------------------------------
// 3 fp32->bf16 flat converts in one dispatch (4M / 2M / 1M elements).
// ---------------------------------------------------------------------------
__global__ __launch_bounds__(256)
void convert3(const float* __restrict__ s0, const float* __restrict__ s1,
              const float* __restrict__ s2, u16* __restrict__ d0,
              u16* __restrict__ d1, u16* __restrict__ d2) {
  int bx = blockIdx.x;
  const float* s; u16* d; size_t base;
  if (bx < 2048)      { s = s0; d = d0; base = (size_t)bx * 2048; }
  else if (bx < 3072) { s = s1; d = d1; base = (size_t)(bx - 2048) * 2048; }
  else                { s = s2; d = d2; base = (size_t)(bx - 3072) * 2048; }
  size_t i = base + (size_t)threadIdx.x * 8;
  const f32x4* p = reinterpret_cast<const f32x4*>(s + i);
  f32x4 a = p[0], b = p[1];
  short8 r;
#pragma unroll
  for (int e = 0; e < 4; e++) { r[e] = (short)f2b(a[e]); r[e + 4] = (short)f2b(b[e]); }
  *reinterpret_cast<short8*>(d + i) = r;
}

// ---------------------------------------------------------------------------
// 4 weight transposes (fp32 W[K x N] -> bf16 WT[N x K]) in one dispatch.
// ---------------------------------------------------------------------------
__global__ __launch_bounds__(256)
void transpose4(const float* __restrict__ W0, const float* __restrict__ W1,
                const float* __restrict__ W2, const float* __restrict__ W3,
                u16* __restrict__ T0, u16* __restrict__ T1,
                u16* __restrict__ T2, u16* __restrict__ T3) {
  const int z = blockIdx.z;
  const float* W; u16* T; int N;
  if (z == 0)      { W = W0; T = T0; N = 2048; }
  else if (z == 1) { W = W1; T = T1; N = 1024; }
  else if (z == 2) { W = W2; T = T2; N = 1024; }
  else             { W = W3; T = T3; N = 1024; }
  const int K = 1024;
  const int n0 = blockIdx.x * 64, k0 = blockIdx.y * 64;
  if (n0 >= N) return;

  __shared__ u16 ld[64 * 66];
  const int tid = threadIdx.x;
#pragma unroll
  for (int rep = 0; rep < 16; rep++) {
    int idx = tid + 256 * rep;
    int kk = idx >> 6, nn = idx & 63;
    ld[kk * 66 + nn] = f2b(W[(size_t)(k0 + kk) * N + n0 + nn]);
  }
  __syncthreads();
#pragma unroll
  for (int rep = 0; rep < 16; rep++) {
    int idx = tid + 256 * rep;
    int nn = idx >> 6, kk = idx & 63;
    T[(size_t)(n0 + nn) * K + k0 + kk] = ld[kk * 66 + nn];
  }
}

// ---------------------------------------------------------------------------
// GEMM (B^T form): C = A[M,K] @ BT[N,K]^T + bias. 128x128 tile, BK=64.
// MODE 0: row-major C.
// MODE 1 (kv): col<1024 -> Kt2 frag-tile order; col>=1024 -> Vt2 frag-tile.
//   Kt2/Vt2: [b][h][tile(16)][4096], K-frag (n=j,k=d), V-frag (n=d,k=j).
// MODE 2 (r): C -> Rt[h][rel][d].
// ---------------------------------------------------------------------------
template <typename OT, int MODE>
__global__ __launch_bounds__(256, 2)
void gemm_bt(const u16* __restrict__ A, const u16* __restrict__ BT,
             const float* __restrict__ bias, OT* __restrict__ C,
             u16* __restrict__ C2, int M, int N, int K)
{
  __shared__ __align__(16) short at[8192];
  __shared__ __align__(16) short bt[8192];

  const int tid = threadIdx.x;
  const int lane = tid & 63, w = tid >> 6;
  const int wr = w >> 1, wc = w & 1;
  const int quad = lane >> 4, ml = lane & 15;
  const int row0 = blockIdx.y * 128, col0 = blockIdx.x * 128;

  f32x4 acc[4][4];
  const f32x4 fzero = {0.f, 0.f, 0.f, 0.f};
#pragma unroll
  for (int i = 0; i < 4; i++)
#pragma unroll
    for (int j = 0; j < 4; j++) acc[i][j] = fzero;

  for (int k0 = 0; k0 < K; k0 += 64) {
    __syncthreads();
#pragma unroll
    for (int cc = 0; cc < 4; cc++) {
      int c = tid + 256 * cc;
      int m = c >> 3, oct = c & 7;
      short8 val = *reinterpret_cast<const short8*>(A + (size_t)(row0 + m) * K + k0 + oct * 8);
      int mc = m >> 4, mll = m & 15, kc = oct >> 2, qd = oct & 3;
      *reinterpret_cast<short8*>(at + (((mc * 2 + kc) * 64) + qd * 16 + mll) * 8) = val;
    }
#pragma unroll
    for (int cc = 0; cc < 4; cc++) {
      int c = tid + 256 * cc;
      int n = c >> 3, oct = c & 7;
      short8 val = *reinterpret_cast<const short8*>(BT + (size_t)(col0 + n) * K + k0 + oct * 8);
      int nc = n >> 4, nl = n & 15, kc = oct >> 2, qd = oct & 3;
      *reinterpret_cast<short8*>(bt + (((nc * 2 + kc) * 64) + qd * 16 + nl) * 8) = val;
    }
    __syncthreads();

    short8 af[4][2], bf[4][2];
#pragma unroll
    for (int mc = 0; mc < 4; mc++)
#pragma unroll
      for (int kc = 0; kc < 2; kc++)
        af[mc][kc] = *reinterpret_cast<const short8*>(at + ((((wr * 4 + mc) * 2 + kc) * 64) + lane) * 8);
#pragma unroll
    for (int nc = 0; nc < 4; nc++)
#pragma unroll
      for (int kc = 0; kc < 2; kc++)
        bf[nc][kc] = *reinterpret_cast<const short8*>(bt + ((((wc * 4 + nc) * 2 + kc) * 64) + lane) * 8);

#pragma unroll
    for (int mc = 0; mc < 4; mc++)
#pragma unroll
      for (int nc = 0; nc < 4; nc++)
#pragma unroll
        for (int kc = 0; kc < 2; kc++)
          acc[mc][nc] = __builtin_amdgcn_mfma_f32_16x16x32_bf16(af[mc][kc], bf[nc][kc], acc[mc][nc], 0, 0, 0);
  }

#pragma unroll
  for (int nc = 0; nc < 4; nc++) {
    int col = col0 + wc * 64 + nc * 16 + ml;
    float bv = bias[col];
#pragma unroll
    for (int mc = 0; mc < 4; mc++) {
#pragma unroll
      for (int reg = 0; reg < 4; reg++) {
        int row = row0 + wr * 64 + mc * 16 + quad * 4 + reg;
        float val = acc[mc][nc][reg] + bv;
        if constexpr (MODE == 0) {
          storeC(C, (size_t)row * N + col, val);
        } else if constexpr (MODE == 1) {
          int j = row >> 2, bb = row & 3;
          int tile = j >> 6, jl = j & 63;
          if (col < 1024) {  // K half: frag (n=j, k=d)
            int h = col >> 6, d = col & 63;
            int ncj = jl >> 4, nlj = jl & 15, kcd = d >> 5, qdd = (d >> 3) & 3, jjd = d & 7;
            C[((size_t)(bb * 16 + h) * 16 + tile) * 4096 +
              ((ncj * 2 + kcd) * 64 + qdd * 16 + nlj) * 8 + jjd] = f2b(val);
          } else {           // V half: frag (n=d, k=j)
            int c2 = col - 1024;
            int h = c2 >> 6, d = c2 & 63;
            int ncd = d >> 4, nld = d & 15, kcj = jl >> 5, qdj = (jl >> 3) & 3, jjj = jl & 7;
            C2[((size_t)(bb * 16 + h) * 16 + tile) * 4096 +
               ((kcj * 4 + ncd) * 64 + qdj * 16 + nld) * 8 + jjj] = f2b(val);
          }
        } else {             // MODE 2: Rt[h][rel][d]
          int h = col >> 6, d = col & 63;
          C[((size_t)h * 1024 + row) * 64 + d] = f2b(val);
        }
      }
    }
  }
}

// ---------------------------------------------------------------------------
// Split-j fused flash-XL. Block = 256 (4 waves) per (i-tile 64, b, h, seg);
// wave w owns rows ig0 = it*64 + w*16. K/V tiles staged by identity copy
// (dense 16B loads -> b128 writes) from frag-tile-ordered Kt2/Vt2; R frags
// direct global (dense 1KB windows); rel-shift via quad-local shuffles.
// Emits unnormalized partials (o, m, l) per seg; combine kernel merges.
// ---------------------------------------------------------------------------
__global__ __launch_bounds__(256, 4)
void flash_xl(const u16* __restrict__ q, const u16* __restrict__ Kt2,
              const u16* __restrict__ Vt2, const u16* __restrict__ Rt,
              const float* __restrict__ u, const float* __restrict__ v,
              float* __restrict__ po, float* __restrict__ pm,
              float* __restrict__ pl)
{
  __shared__ __align__(16) short kb[4096];
  __shared__ __align__(16) short vb[4096];
  __shared__ __align__(16) short pt[4][1024];

  const int tid = threadIdx.x, lane = tid & 63, w = tid >> 6;
  const int quad = lane >> 4, ml = lane & 15;
  const int x = blockIdx.x;
  const int it = 7 - (x >> 1), seg = x & 1;  // longest i-tiles dispatched first
  const int b = blockIdx.y, h = blockIdx.z;
  const int i0 = it * 64, ig0 = i0 + w * 16;

  const u16* Kbase = Kt2 + ((size_t)(b * 16 + h) * 16) * 4096;
  const u16* Vbase = Vt2 + ((size_t)(b * 16 + h) * 16) * 4096;
  const u16* Rp = Rt + (size_t)h * 65536;

  // Q fragments, pre-scaled by 1/8: rows ig0+ml, k = kc*32+quad*8+e
  short8 qu[2], qvf[2];
  {
    int ig = ig0 + ml;
#pragma unroll
    for (int kc = 0; kc < 2; kc++) {
      int dbase = kc * 32 + quad * 8;
      short8 qq = *reinterpret_cast<const short8*>(q + ((size_t)ig * BSZ + b) * 1024 + h * 64 + dbase);
      const f32x4* up = reinterpret_cast<const f32x4*>(u + h * 64 + dbase);
      const f32x4* vp = reinterpret_cast<const f32x4*>(v + h * 64 + dbase);
      f32x4 u0 = up[0], u1 = up[1], v0 = vp[0], v1 = vp[1];
#pragma unroll
      for (int e = 0; e < 8; e++) {
        float qf = b2f((u16)qq[e]);
        float uu = (e < 4) ? u0[e] : u1[e - 4];
        float vv = (e < 4) ? v0[e] : v1[e - 4];
        qu[kc][e]  = (short)f2b((qf + uu) * 0.125f);
        qvf[kc][e] = (short)f2b((qf + vv) * 0.125f);
      }
    }
  }

  const f32x4 fzero = {0.f, 0.f, 0.f, 0.f};
  f32x4 o_acc[4];
#pragma unroll
  for (int i = 0; i < 4; i++) o_acc[i] = fzero;
  float m_run[4], l_run[4];
#pragma unroll
  for (int i = 0; i < 4; i++) { m_run[i] = -1e30f; l_run[i] = 0.f; }

  const int nt = it + 9;          // total tiles covering j <= i0+63+512
  const int nt0 = (nt + 1) >> 1;  // seg0 tile count
  const int ts = seg ? nt0 : 0, te = seg ? nt : nt0;

  for (int t = ts; t < te; t++) {
    const int j0 = t * 64;
    // ---- identity-copy staging: dense 16B global loads (issued pre-barrier)
    const u16* kg = Kbase + (size_t)t * 4096;
    const u16* vg = Vbase + (size_t)t * 4096;
    short8 k0 = *reinterpret_cast<const short8*>(kg + tid * 8);
    short8 k1 = *reinterpret_cast<const short8*>(kg + 2048 + tid * 8);
    short8 v0 = *reinterpret_cast<const short8*>(vg + tid * 8);
    short8 v1 = *reinterpret_cast<const short8*>(vg + 2048 + tid * 8);
    __syncthreads();  // previous tile fully consumed
    *reinterpret_cast<short8*>(kb + tid * 8) = k0;
    *reinterpret_cast<short8*>(kb + 2048 + tid * 8) = k1;
    *reinterpret_cast<short8*>(vb + tid * 8) = v0;
    *reinterpret_cast<short8*>(vb + 2048 + tid * 8) = v1;
    __syncthreads();  // staging visible

    // ---- content scores: K B-frags from LDS
    f32x4 sc[4];
#pragma unroll
    for (int nc = 0; nc < 4; nc++) {
      sc[nc] = fzero;
#pragma unroll
      for (int kc = 0; kc < 2; kc++) {
        short8 kf = *reinterpret_cast<const short8*>(kb + ((nc * 2 + kc) * 64 + lane) * 8);
        sc[nc] = __builtin_amdgcn_mfma_f32_16x16x32_bf16(qu[kc], kf, sc[nc], 0, 0, 0);
      }
    }
    // ---- position strip: R B-frags direct from global (dense 1KB windows)
    const int relstart = j0 - ig0 + 496;  // >= 0
    f32x4 p2[5];
#pragma unroll
    for (int c = 0; c < 5; c++) {
      p2[c] = fzero;
      int rel = relstart + c * 16 + ml;
      if (rel > 1023) rel = 1023;  // clamped rows are masked below
      const u16* rp = Rp + (size_t)rel * 64 + quad * 8;
#pragma unroll
      for (int kc = 0; kc < 2; kc++) {
        short8 rf = *reinterpret_cast<const short8*>(rp + kc * 32);
        p2[c] = __builtin_amdgcn_mfma_f32_16x16x32_bf16(qvf[kc], rf, p2[c], 0, 0, 0);
      }
    }

    // ---- rel-shift gather (quad-local shuffles) + mask + online softmax
    const bool anymask = (j0 + 63) > (ig0 + PREV);
    float pv_[4][4];
    float tmax[4] = {-1e30f, -1e30f, -1e30f, -1e30f};
#pragma unroll
    for (int reg = 0; reg < 4; reg++) {
      int rowl = quad * 4 + reg;
      int src = quad * 16 + ((ml - rowl - 1) & 15);
      bool hi = ml > rowl;
      float sh[5];
#pragma unroll
      for (int c = 0; c < 5; c++) sh[c] = __shfl(p2[c][reg], src, 64);
#pragma unroll
      for (int nc = 0; nc < 4; nc++) {
        float s = sc[nc][reg] + (hi ? sh[nc + 1] : sh[nc]);
        if (anymask) {
          int jg = j0 + nc * 16 + ml;
          if (jg > ig0 + rowl + PREV) s = -1e30f;
        }
        pv_[nc][reg] = s;
        tmax[reg] = fmaxf(tmax[reg], s);
      }
    }
#pragma unroll
    for (int reg = 0; reg < 4; reg++) {
      float tm = tmax[reg];
#pragma unroll
      for (int off = 1; off < 16; off <<= 1) tm = fmaxf(tm, __shfl_xor(tm, off, 64));
      float mnew = fmaxf(m_run[reg], tm);
      float alpha = __expf(m_run[reg] - mnew);
      float rs = 0.f;
#pragma unroll
      for (int nc = 0; nc < 4; nc++) {
        float p = __expf(pv_[nc][reg] - mnew);
        pv_[nc][reg] = p;
        rs += p;
      }
#pragma unroll
      for (int off = 1; off < 16; off <<= 1) rs += __shfl_xor(rs, off, 64);
      l_run[reg] = l_run[reg] * alpha + rs;
      m_run[reg] = mnew;
#pragma unroll
      for (int nc = 0; nc < 4; nc++) o_acc[nc][reg] *= alpha;
    }

    // ---- P (C layout) -> bf16 A-frag via per-wave LDS (wave-order safe)
#pragma unroll
    for (int nc = 0; nc < 4; nc++) {
      int jl = nc * 16 + ml;
      int kc = nc >> 1, qdj = (jl >> 3) & 3, jj = ml & 7;
#pragma unroll
      for (int reg = 0; reg < 4; reg++) {
        int rowl = quad * 4 + reg;
        pt[w][(kc * 64 + qdj * 16 + rowl) * 8 + jj] = (short)f2b(pv_[nc][reg]);
      }
    }
    short8 pf[2];
    pf[0] = *reinterpret_cast<const short8*>(pt[w] + (0 * 64 + lane) * 8);
    pf[1] = *reinterpret_cast<const short8*>(pt[w] + (1 * 64 + lane) * 8);

    // ---- PV: V B-frags from LDS (k = kc*32 + quad*8 + e)
#pragma unroll
    for (int ncd = 0; ncd < 4; ncd++)
#pragma unroll
      for (int kc = 0; kc < 2; kc++) {
        short8 vf = *reinterpret_cast<const short8*>(vb + ((kc * 4 + ncd) * 64 + lane) * 8);
        o_acc[ncd] = __builtin_amdgcn_mfma_f32_16x16x32_bf16(pf[kc], vf, o_acc[ncd], 0, 0, 0);
      }
  }

  // ---- write unnormalized partials
#pragma unroll
  for (int reg = 0; reg < 4; reg++) {
    int ig = ig0 + quad * 4 + reg;
    size_t ridx = ((size_t)(seg * 512 + ig) * 4 + b) * 16 + h;
    if (ml == 0) { pm[ridx] = m_run[reg]; pl[ridx] = l_run[reg]; }
#pragma unroll
    for (int ncd = 0; ncd < 4; ncd++)
      po[ridx * 64 + ncd * 16 + ml] = o_acc[ncd][reg];
  }
}

// ---------------------------------------------------------------------------
// Merge the two j-segments: av = (o1*e^{m1-m} + o2*e^{m2-m}) / (l1*... + l2*...)
// ---------------------------------------------------------------------------
__global__ __launch_bounds__(256)
void combine(const float* __restrict__ po, const float* __restrict__ pm,
             const float* __restrict__ pl, u16* __restrict__ av) {
  int idx = blockIdx.x * 256 + threadIdx.x;  // 2,097,152 total
  int d = idx & 63;
  int ridx = idx >> 6;                       // (ig*4+b)*16+h
  float m1 = pm[ridx], m2 = pm[32768 + ridx];
  float l1 = pl[ridx], l2 = pl[32768 + ridx];
  float o1 = po[(size_t)ridx * 64 + d];
  float o2 = po[2097152 + (size_t)ridx * 64 + d];
  float m = fmaxf(m1, m2);
  float a1 = __expf(m1 - m), a2 = __expf(m2 - m);
  float l = l1 * a1 + l2 * a2;
  av[(size_t)ridx * 64 + d] = f2b((o1 * a1 + o2 * a2) / l);
}

// ---------------------------------------------------------------------------
extern "C" void kernel_launch(void* const* d_in, const int* in_sizes, int n_in,
                              void* d_out, int out_size, void* d_ws, size_t ws_size,
                              hipStream_t stream) {
  (void)in_sizes; (void)n_in; (void)out_size; (void)ws_size;

  const float* inputs  = (const float*)d_in[0];   // (512,4,1024)
  const float* pos_emb = (const float*)d_in[1];   // (1024,1,1024)
  const float* full_in = (const float*)d_in[2];   // (1024,4,1024)
  const float* u       = (const float*)d_in[3];   // (16,64)
  const float* v       = (const float*)d_in[4];   // (16,64)
  const float* W_kv    = (const float*)d_in[5];   // (1024,2048)
  const float* b_kv    = (const float*)d_in[6];   // (2048,)
  const float* W_q     = (const float*)d_in[7];   // (1024,1024)
  const float* b_q     = (const float*)d_in[8];
  const float* W_pos   = (const float*)d_in[9];   // (1024,1024)
  const float* b_pos   = (const float*)d_in[10];
  const float* W_proj  = (const float*)d_in[11];  // (1024,1024)
  const float* b_proj  = (const float*)d_in[12];
  // d_in[13] = mask (bool) — recomputed analytically (j > i + 512)
  float* out = (float*)d_out;

  char* ws = (char*)d_ws;
  u16* Kt2   = (u16*)(ws);                  //  8 MB: [4][16][16 tiles][4096] frag order
  u16* Vt2   = (u16*)(ws + ( 8u << 20));    //  8 MB: same shape, V frag order
  u16* qq    = (u16*)(ws + (16u << 20));    //  4 MB: 2048x1024
  u16* Rt    = (u16*)(ws + (20u << 20));    //  2 MB: [16 h][1024 rel][64 d]
  u16* av    = (u16*)(ws + (22u << 20));    //  4 MB: 2048x1024
  u16* WkvT  = (u16*)(ws + (26u << 20));    //  4 MB
  u16* WqT   = (u16*)(ws + (30u << 20));    //  2 MB
  u16* WposT = (u16*)(ws + (32u << 20));    //  2 MB
  u16* WprojT= (u16*)(ws + (34u << 20));    //  2 MB
  u16* fibf  = (u16*)(ws + (36u << 20));    //  8 MB (dead after kv GEMM)
  u16* inbf  = (u16*)(ws + (44u << 20));    //  4 MB (dead after q GEMM)
  u16* pebf  = (u16*)(ws + (48u << 20));    //  2 MB (dead after r GEMM)
  float* po  = (float*)(ws + (36u << 20));  // 16 MB partial O (overlays the above)
  float* pm  = (float*)(ws + (52u << 20));  // 256 KB partial m
  float* pl  = (float*)(ws + (52u << 20) + (256u << 10));  // 256 KB partial l

  // --- precompute
  hipLaunchKernelGGL(convert3, dim3(3584), dim3(256), 0, stream,
                     full_in, inputs, pos_emb, fibf, inbf, pebf);
  hipLaunchKernelGGL(transpose4, dim3(32, 16, 4), dim3(256), 0, stream,
                     W_kv, W_q, W_pos, W_proj, WkvT, WqT, WposT, WprojT);

  // --- GEMMs
  hipLaunchKernelGGL((gemm_bt<u16, 1>), dim3(16, 32), dim3(256), 0, stream,
                     fibf, WkvT, b_kv, Kt2, Vt2, 4096, 2048, 1024);
  hipLaunchKernelGGL((gemm_bt<u16, 0>), dim3(8, 16), dim3(256), 0, stream,
                     inbf, WqT, b_q, qq, (u16*)nullptr, 2048, 1024, 1024);
  hipLaunchKernelGGL((gemm_bt<u16, 2>), dim3(8, 8), dim3(256), 0, stream,
                     pebf, WposT, b_pos, Rt, (u16*)nullptr, 1024, 1024, 1024);
  // --- split-j fused attention + combine
  hipLaunchKernelGGL(flash_xl, dim3(16, 4, 16), dim3(256), 0, stream,
                     qq, Kt2, Vt2, Rt, u, v, po, pm, pl);
  hipLaunchKernelGGL(combine, dim3(8192), dim3(256), 0, stream, po, pm, pl, av);
  // --- output projection
  hipLaunchKernelGGL((gemm_bt<float, 0>), dim3(8, 16), dim3(256), 0, stream,
                     av, WprojT, b_proj, out, (u16*)nullptr, 2048, 1024, 1024);
}

// Round 11
// 299.856 us; speedup vs baseline: 1.2104x; 1.0123x over previous
//
#include <hip/hip_runtime.h>

// AttentionXL (TransformerXL relative attention), MI355X gfx950.
// fp32 I/O. convert3 + transpose4 -> kv GEMM (epilogue emits Kt2/Vt2 in MFMA
// frag-tile order) -> q GEMM -> r GEMM (Rt[h][rel][d]) -> split-j flash ->
// combine -> proj GEMM.
// Round 11: round-10 design with the load_lds16 type fix (void* LDS dest).

typedef unsigned short u16;
typedef short short8 __attribute__((ext_vector_type(8)));
typedef float f32x4 __attribute__((ext_vector_type(4)));

#define BSZ 4
#define PREV 512

__device__ __forceinline__ float b2f(u16 u) {
  union { unsigned int i; float f; } x; x.i = ((unsigned int)u) << 16; return x.f;
}
__device__ __forceinline__ u16 f2b(float f) {
  union { float f; unsigned int i; } x; x.f = f;
  unsigned int u = x.i;
  return (u16)((u + 0x7fffu + ((u >> 16) & 1u)) >> 16);
}
__device__ __forceinline__ void storeC(u16* C, size_t idx, float v) { C[idx] = f2b(v); }
__device__ __forceinline__ void storeC(float* C, size_t idx, float v) { C[idx] = v; }

// async 16B/lane global->LDS DMA; lds dest = wave-uniform base + lane*16
__device__ __forceinline__ void load_lds16(const u16* g, void* l) {
  __builtin_amdgcn_global_load_lds(
      (const __attribute__((address_space(1))) unsigned int*)g,
      (__attribute__((address_space(3))) unsigned int*)l, 16, 0, 0);
}

// ---------------------------------------------------------------------------
// 3 fp32->bf16 flat converts in one dispatch (4M / 2M / 1M elements).
// ---------------------------------------------------------------------------
__global__ __launch_bounds__(256)
void convert3(const float* __restrict__ s0, const float* __restrict__ s1,
              const float* __restrict__ s2, u16* __restrict__ d0,
              u16* __restrict__ d1, u16* __restrict__ d2) {
  int bx = blockIdx.x;
  const float* s; u16* d; size_t base;
  if (bx < 2048)      { s = s0; d = d0; base = (size_t)bx * 2048; }
  else if (bx < 3072) { s = s1; d = d1; base = (size_t)(bx - 2048) * 2048; }
  else                { s = s2; d = d2; base = (size_t)(bx - 3072) * 2048; }
  size_t i = base + (size_t)threadIdx.x * 8;
  const f32x4* p = reinterpret_cast<const f32x4*>(s + i);
  f32x4 a = p[0], b = p[1];
  short8 r;
#pragma unroll
  for (int e = 0; e < 4; e++) { r[e] = (short)f2b(a[e]); r[e + 4] = (short)f2b(b[e]); }
  *reinterpret_cast<short8*>(d + i) = r;
}

// ---------------------------------------------------------------------------
// 4 weight transposes (fp32 W[K x N] -> bf16 WT[N x K]) in one dispatch.
// ---------------------------------------------------------------------------
__global__ __launch_bounds__(256)
void transpose4(const float* __restrict__ W0, const float* __restrict__ W1,
                const float* __restrict__ W2, const float* __restrict__ W3,
                u16* __restrict__ T0, u16* __restrict__ T1,
                u16* __restrict__ T2, u16* __restrict__ T3) {
  const int z = blockIdx.z;
  const float* W; u16* T; int N;
  if (z == 0)      { W = W0; T = T0; N = 2048; }
  else if (z == 1) { W = W1; T = T1; N = 1024; }
  else if (z == 2) { W = W2; T = T2; N = 1024; }
  else             { W = W3; T = T3; N = 1024; }
  const int K = 1024;
  const int n0 = blockIdx.x * 64, k0 = blockIdx.y * 64;
  if (n0 >= N) return;

  __shared__ u16 ld[64 * 66];
  const int tid = threadIdx.x;
#pragma unroll
  for (int rep = 0; rep < 16; rep++) {
    int idx = tid + 256 * rep;
    int kk = idx >> 6, nn = idx & 63;
    ld[kk * 66 + nn] = f2b(W[(size_t)(k0 + kk) * N + n0 + nn]);
  }
  __syncthreads();
#pragma unroll
  for (int rep = 0; rep < 16; rep++) {
    int idx = tid + 256 * rep;
    int nn = idx >> 6, kk = idx & 63;
    T[(size_t)(n0 + nn) * K + k0 + kk] = ld[kk * 66 + nn];
  }
}

// ---------------------------------------------------------------------------
// GEMM (B^T form): C = A[M,K] @ BT[N,K]^T + bias. 128x128 tile, BK=64.
// Staging via global_load_lds (16B/lane DMA, frag-order LDS, no VGPR trip):
// wave w stages A chunks 4w..4w+3 and B chunks 4w..4w+3 (1KB each).
// MODE 0: row-major C. MODE 1 (kv): Kt2/Vt2 frag-tile order. MODE 2: Rt.
// ---------------------------------------------------------------------------
template <typename OT, int MODE>
__global__ __launch_bounds__(256, 2)
void gemm_bt(const u16* __restrict__ A, const u16* __restrict__ BT,
             const float* __restrict__ bias, OT* __restrict__ C,
             u16* __restrict__ C2, int M, int N, int K)
{
  __shared__ __align__(16) short at[8192];  // 16 chunks of 1KB, frag order
  __shared__ __align__(16) short bt[8192];

  const int tid = threadIdx.x;
  const int lane = tid & 63, w = tid >> 6;
  const int wr = w >> 1, wc = w & 1;
  const int quad = lane >> 4, ml = lane & 15;
  const int row0 = blockIdx.y * 128, col0 = blockIdx.x * 128;

  // per-lane source row/koff pieces for the DMA staging
  const int srow = lane & 15;          // row within 16-row group
  const int skoff = (lane >> 4) * 8;   // k offset within 32-k half

  f32x4 acc[4][4];
  const f32x4 fzero = {0.f, 0.f, 0.f, 0.f};
#pragma unroll
  for (int i = 0; i < 4; i++)
#pragma unroll
    for (int j = 0; j < 4; j++) acc[i][j] = fzero;

  for (int k0 = 0; k0 < K; k0 += 64) {
    __syncthreads();  // previous tile fully consumed
#pragma unroll
    for (int i = 0; i < 4; i++) {
      int c = 4 * w + i;                 // chunk index 0..15
      int mc = c >> 1, kc = c & 1;
      load_lds16(A + (size_t)(row0 + mc * 16 + srow) * K + k0 + kc * 32 + skoff,
                 (void*)(at + c * 512));
      load_lds16(BT + (size_t)(col0 + mc * 16 + srow) * K + k0 + kc * 32 + skoff,
                 (void*)(bt + c * 512));
    }
    __syncthreads();  // drains vmcnt; staging visible

    short8 af[4][2], bf[4][2];
#pragma unroll
    for (int mc = 0; mc < 4; mc++)
#pragma unroll
      for (int kc = 0; kc < 2; kc++)
        af[mc][kc] = *reinterpret_cast<const short8*>(at + ((((wr * 4 + mc) * 2 + kc) * 64) + lane) * 8);
#pragma unroll
    for (int nc = 0; nc < 4; nc++)
#pragma unroll
      for (int kc = 0; kc < 2; kc++)
        bf[nc][kc] = *reinterpret_cast<const short8*>(bt + ((((wc * 4 + nc) * 2 + kc) * 64) + lane) * 8);

#pragma unroll
    for (int mc = 0; mc < 4; mc++)
#pragma unroll
      for (int nc = 0; nc < 4; nc++)
#pragma unroll
        for (int kc = 0; kc < 2; kc++)
          acc[mc][nc] = __builtin_amdgcn_mfma_f32_16x16x32_bf16(af[mc][kc], bf[nc][kc], acc[mc][nc], 0, 0, 0);
  }

#pragma unroll
  for (int nc = 0; nc < 4; nc++) {
    int col = col0 + wc * 64 + nc * 16 + ml;
    float bv = bias[col];
#pragma unroll
    for (int mc = 0; mc < 4; mc++) {
#pragma unroll
      for (int reg = 0; reg < 4; reg++) {
        int row = row0 + wr * 64 + mc * 16 + quad * 4 + reg;
        float val = acc[mc][nc][reg] + bv;
        if constexpr (MODE == 0) {
          storeC(C, (size_t)row * N + col, val);
        } else if constexpr (MODE == 1) {
          int j = row >> 2, bb = row & 3;
          int tile = j >> 6, jl = j & 63;
          if (col < 1024) {  // K half: frag (n=j, k=d)
            int h = col >> 6, d = col & 63;
            int ncj = jl >> 4, nlj = jl & 15, kcd = d >> 5, qdd = (d >> 3) & 3, jjd = d & 7;
            C[((size_t)(bb * 16 + h) * 16 + tile) * 4096 +
              ((ncj * 2 + kcd) * 64 + qdd * 16 + nlj) * 8 + jjd] = f2b(val);
          } else {           // V half: frag (n=d, k=j)
            int c2 = col - 1024;
            int h = c2 >> 6, d = c2 & 63;
            int ncd = d >> 4, nld = d & 15, kcj = jl >> 5, qdj = (jl >> 3) & 3, jjj = jl & 7;
            C2[((size_t)(bb * 16 + h) * 16 + tile) * 4096 +
               ((kcj * 4 + ncd) * 64 + qdj * 16 + nld) * 8 + jjj] = f2b(val);
          }
        } else {             // MODE 2: Rt[h][rel][d]
          int h = col >> 6, d = col & 63;
          C[((size_t)h * 1024 + row) * 64 + d] = f2b(val);
        }
      }
    }
  }
}

// ---------------------------------------------------------------------------
// Split-j fused flash-XL. Block = 256 (4 waves) per (i-tile 64, b, h, seg).
// K/V identity chunks register-prefetched one j-tile ahead. R frags direct
// global; rel-shift via quad-local shuffles. Emits unnormalized partials.
// ---------------------------------------------------------------------------
__global__ __launch_bounds__(256, 4)
void flash_xl(const u16* __restrict__ q, const u16* __restrict__ Kt2,
              const u16* __restrict__ Vt2, const u16* __restrict__ Rt,
              const float* __restrict__ u, const float* __restrict__ v,
              float* __restrict__ po, float* __restrict__ pm,
              float* __restrict__ pl)
{
  __shared__ __align__(16) short kb[4096];
  __shared__ __align__(16) short vb[4096];
  __shared__ __align__(16) short pt[4][1024];

  const int tid = threadIdx.x, lane = tid & 63, w = tid >> 6;
  const int quad = lane >> 4, ml = lane & 15;
  const int x = blockIdx.x;
  const int it = 7 - (x >> 1), seg = x & 1;  // longest i-tiles dispatched first
  const int b = blockIdx.y, h = blockIdx.z;
  const int i0 = it * 64, ig0 = i0 + w * 16;

  const u16* Kbase = Kt2 + ((size_t)(b * 16 + h) * 16) * 4096;
  const u16* Vbase = Vt2 + ((size_t)(b * 16 + h) * 16) * 4096;
  const u16* Rp = Rt + (size_t)h * 65536;

  // Q fragments, pre-scaled by 1/8: rows ig0+ml, k = kc*32+quad*8+e
  short8 qu[2], qvf[2];
  {
    int ig = ig0 + ml;
#pragma unroll
    for (int kc = 0; kc < 2; kc++) {
      int dbase = kc * 32 + quad * 8;
      short8 qq = *reinterpret_cast<const short8*>(q + ((size_t)ig * BSZ + b) * 1024 + h * 64 + dbase);
      const f32x4* up = reinterpret_cast<const f32x4*>(u + h * 64 + dbase);
      const f32x4* vp = reinterpret_cast<const f32x4*>(v + h * 64 + dbase);
      f32x4 u0 = up[0], u1 = up[1], v0 = vp[0], v1 = vp[1];
#pragma unroll
      for (int e = 0; e < 8; e++) {
        float qf = b2f((u16)qq[e]);
        float uu = (e < 4) ? u0[e] : u1[e - 4];
        float vv = (e < 4) ? v0[e] : v1[e - 4];
        qu[kc][e]  = (short)f2b((qf + uu) * 0.125f);
        qvf[kc][e] = (short)f2b((qf + vv) * 0.125f);
      }
    }
  }

  const f32x4 fzero = {0.f, 0.f, 0.f, 0.f};
  f32x4 o_acc[4];
#pragma unroll
  for (int i = 0; i < 4; i++) o_acc[i] = fzero;
  float m_run[4], l_run[4];
#pragma unroll
  for (int i = 0; i < 4; i++) { m_run[i] = -1e30f; l_run[i] = 0.f; }

  const int nt = it + 9;          // total tiles covering j <= i0+63+512
  const int nt0 = (nt + 1) >> 1;  // seg0 tile count
  const int ts = seg ? nt0 : 0, te = seg ? nt : nt0;

  // ---- prologue: prefetch tile ts's identity chunks into registers
  short8 pk0, pk1, pv0, pv1;
  {
    const u16* kg = Kbase + (size_t)ts * 4096;
    const u16* vg = Vbase + (size_t)ts * 4096;
    pk0 = *reinterpret_cast<const short8*>(kg + tid * 8);
    pk1 = *reinterpret_cast<const short8*>(kg + 2048 + tid * 8);
    pv0 = *reinterpret_cast<const short8*>(vg + tid * 8);
    pv1 = *reinterpret_cast<const short8*>(vg + 2048 + tid * 8);
  }

  for (int t = ts; t < te; t++) {
    const int j0 = t * 64;
    __syncthreads();  // previous tile fully consumed
    *reinterpret_cast<short8*>(kb + tid * 8) = pk0;
    *reinterpret_cast<short8*>(kb + 2048 + tid * 8) = pk1;
    *reinterpret_cast<short8*>(vb + tid * 8) = pv0;
    *reinterpret_cast<short8*>(vb + 2048 + tid * 8) = pv1;
    __syncthreads();  // staging visible

    // ---- issue next tile's prefetch (latency hidden behind this tile's body)
    if (t + 1 < te) {
      const u16* kg = Kbase + (size_t)(t + 1) * 4096;
      const u16* vg = Vbase + (size_t)(t + 1) * 4096;
      pk0 = *reinterpret_cast<const short8*>(kg + tid * 8);
      pk1 = *reinterpret_cast<const short8*>(kg + 2048 + tid * 8);
      pv0 = *reinterpret_cast<const short8*>(vg + tid * 8);
      pv1 = *reinterpret_cast<const short8*>(vg + 2048 + tid * 8);
    }

    // ---- content scores: K B-frags from LDS
    f32x4 sc[4];
#pragma unroll
    for (int nc = 0; nc < 4; nc++) {
      sc[nc] = fzero;
#pragma unroll
      for (int kc = 0; kc < 2; kc++) {
        short8 kf = *reinterpret_cast<const short8*>(kb + ((nc * 2 + kc) * 64 + lane) * 8);
        sc[nc] = __builtin_amdgcn_mfma_f32_16x16x32_bf16(qu[kc], kf, sc[nc], 0, 0, 0);
      }
    }
    // ---- position strip: R B-frags direct from global (dense 1KB windows)
    const int relstart = j0 - ig0 + 496;  // >= 0
    f32x4 p2[5];
#pragma unroll
    for (int c = 0; c < 5; c++) {
      p2[c] = fzero;
      int rel = relstart + c * 16 + ml;
      if (rel > 1023) rel = 1023;  // clamped rows are masked below
      const u16* rp = Rp + (size_t)rel * 64 + quad * 8;
#pragma unroll
      for (int kc = 0; kc < 2; kc++) {
        short8 rf = *reinterpret_cast<const short8*>(rp + kc * 32);
        p2[c] = __builtin_amdgcn_mfma_f32_16x16x32_bf16(qvf[kc], rf, p2[c], 0, 0, 0);
      }
    }

    // ---- rel-shift gather (quad-local shuffles) + mask + online softmax
    const bool anymask = (j0 + 63) > (ig0 + PREV);
    float pv_[4][4];
    float tmax[4] = {-1e30f, -1e30f, -1e30f, -1e30f};
#pragma unroll
    for (int reg = 0; reg < 4; reg++) {
      int rowl = quad * 4 + reg;
      int src = quad * 16 + ((ml - rowl - 1) & 15);
      bool hi = ml > rowl;
      float sh[5];
#pragma unroll
      for (int c = 0; c < 5; c++) sh[c] = __shfl(p2[c][reg], src, 64);
#pragma unroll
      for (int nc = 0; nc < 4; nc++) {
        float s = sc[nc][reg] + (hi ? sh[nc + 1] : sh[nc]);
        if (anymask) {
          int jg = j0 + nc * 16 + ml;
          if (jg > ig0 + rowl + PREV) s = -1e30f;
        }
        pv_[nc][reg] = s;
        tmax[reg] = fmaxf(tmax[reg], s);
      }
    }
#pragma unroll
    for (int reg = 0; reg < 4; reg++) {
      float tm = tmax[reg];
#pragma unroll
      for (int off = 1; off < 16; off <<= 1) tm = fmaxf(tm, __shfl_xor(tm, off, 64));
      float mnew = fmaxf(m_run[reg], tm);
      float alpha = __expf(m_run[reg] - mnew);
      float rs = 0.f;
#pragma unroll
      for (int nc = 0; nc < 4; nc++) {
        float p = __expf(pv_[nc][reg] - mnew);
        pv_[nc][reg] = p;
        rs += p;
      }
#pragma unroll
      for (int off = 1; off < 16; off <<= 1) rs += __shfl_xor(rs, off, 64);
      l_run[reg] = l_run[reg] * alpha + rs;
      m_run[reg] = mnew;
#pragma unroll
      for (int nc = 0; nc < 4; nc++) o_acc[nc][reg] *= alpha;
    }

    // ---- P (C layout) -> bf16 A-frag via per-wave LDS (wave-order safe)
#pragma unroll
    for (int nc = 0; nc < 4; nc++) {
      int jl = nc * 16 + ml;
      int kc = nc >> 1, qdj = (jl >> 3) & 3, jj = ml & 7;
#pragma unroll
      for (int reg = 0; reg < 4; reg++) {
        int rowl = quad * 4 + reg;
        pt[w][(kc * 64 + qdj * 16 + rowl) * 8 + jj] = (short)f2b(pv_[nc][reg]);
      }
    }
    short8 pf[2];
    pf[0] = *reinterpret_cast<const short8*>(pt[w] + (0 * 64 + lane) * 8);
    pf[1] = *reinterpret_cast<const short8*>(pt[w] + (1 * 64 + lane) * 8);

    // ---- PV: V B-frags from LDS (k = kc*32 + quad*8 + e)
#pragma unroll
    for (int ncd = 0; ncd < 4; ncd++)
#pragma unroll
      for (int kc = 0; kc < 2; kc++) {
        short8 vf = *reinterpret_cast<const short8*>(vb + ((kc * 4 + ncd) * 64 + lane) * 8);
        o_acc[ncd] = __builtin_amdgcn_mfma_f32_16x16x32_bf16(pf[kc], vf, o_acc[ncd], 0, 0, 0);
      }
  }

  // ---- write unnormalized partials
#pragma unroll
  for (int reg = 0; reg < 4; reg++) {
    int ig = ig0 + quad * 4 + reg;
    size_t ridx = ((size_t)(seg * 512 + ig) * 4 + b) * 16 + h;
    if (ml == 0) { pm[ridx] = m_run[reg]; pl[ridx] = l_run[reg]; }
#pragma unroll
    for (int ncd = 0; ncd < 4; ncd++)
      po[ridx * 64 + ncd * 16 + ml] = o_acc[ncd][reg];
  }
}

// ---------------------------------------------------------------------------
// Merge the two j-segments.
// ---------------------------------------------------------------------------
__global__ __launch_bounds__(256)
void combine(const float* __restrict__ po, const float* __restrict__ pm,
             const float* __restrict__ pl, u16* __restrict__ av) {
  int idx = blockIdx.x * 256 + threadIdx.x;  // 2,097,152 total
  int d = idx & 63;
  int ridx = idx >> 6;                       // (ig*4+b)*16+h
  float m1 = pm[ridx], m2 = pm[32768 + ridx];
  float l1 = pl[ridx], l2 = pl[32768 + ridx];
  float o1 = po[(size_t)ridx * 64 + d];
  float o2 = po[2097152 + (size_t)ridx * 64 + d];
  float m = fmaxf(m1, m2);
  float a1 = __expf(m1 - m), a2 = __expf(m2 - m);
  float l = l1 * a1 + l2 * a2;
  av[(size_t)ridx * 64 + d] = f2b((o1 * a1 + o2 * a2) / l);
}

// ---------------------------------------------------------------------------
extern "C" void kernel_launch(void* const* d_in, const int* in_sizes, int n_in,
                              void* d_out, int out_size, void* d_ws, size_t ws_size,
                              hipStream_t stream) {
  (void)in_sizes; (void)n_in; (void)out_size; (void)ws_size;

  const float* inputs  = (const float*)d_in[0];   // (512,4,1024)
  const float* pos_emb = (const float*)d_in[1];   // (1024,1,1024)
  const float* full_in = (const float*)d_in[2];   // (1024,4,1024)
  const float* u       = (const float*)d_in[3];   // (16,64)
  const float* v       = (const float*)d_in[4];   // (16,64)
  const float* W_kv    = (const float*)d_in[5];   // (1024,2048)
  const float* b_kv    = (const float*)d_in[6];   // (2048,)
  const float* W_q     = (const float*)d_in[7];   // (1024,1024)
  const float* b_q     = (const float*)d_in[8];
  const float* W_pos   = (const float*)d_in[9];   // (1024,1024)
  const float* b_pos   = (const float*)d_in[10];
  const float* W_proj  = (const float*)d_in[11];  // (1024,1024)
  const float* b_proj  = (const float*)d_in[12];
  // d_in[13] = mask (bool) — recomputed analytically (j > i + 512)
  float* out = (float*)d_out;

  char* ws = (char*)d_ws;
  u16* Kt2   = (u16*)(ws);                  //  8 MB: [4][16][16 tiles][4096] frag order
  u16* Vt2   = (u16*)(ws + ( 8u << 20));    //  8 MB: same shape, V frag order
  u16* qq    = (u16*)(ws + (16u << 20));    //  4 MB: 2048x1024
  u16* Rt    = (u16*)(ws + (20u << 20));    //  2 MB: [16 h][1024 rel][64 d]
  u16* av    = (u16*)(ws + (22u << 20));    //  4 MB: 2048x1024
  u16* WkvT  = (u16*)(ws + (26u << 20));    //  4 MB
  u16* WqT   = (u16*)(ws + (30u << 20));    //  2 MB
  u16* WposT = (u16*)(ws + (32u << 20));    //  2 MB
  u16* WprojT= (u16*)(ws + (34u << 20));    //  2 MB
  u16* fibf  = (u16*)(ws + (36u << 20));    //  8 MB (dead after kv GEMM)
  u16* inbf  = (u16*)(ws + (44u << 20));    //  4 MB (dead after q GEMM)
  u16* pebf  = (u16*)(ws + (48u << 20));    //  2 MB (dead after r GEMM)
  float* po  = (float*)(ws + (36u << 20));  // 16 MB partial O (overlays the above)
  float* pm  = (float*)(ws + (52u << 20));  // 256 KB partial m
  float* pl  = (float*)(ws + (52u << 20) + (256u << 10));  // 256 KB partial l

  // --- precompute
  hipLaunchKernelGGL(convert3, dim3(3584), dim3(256), 0, stream,
                     full_in, inputs, pos_emb, fibf, inbf, pebf);
  hipLaunchKernelGGL(transpose4, dim3(32, 16, 4), dim3(256), 0, stream,
                     W_kv, W_q, W_pos, W_proj, WkvT, WqT, WposT, WprojT);

  // --- GEMMs
  hipLaunchKernelGGL((gemm_bt<u16, 1>), dim3(16, 32), dim3(256), 0, stream,
                     fibf, WkvT, b_kv, Kt2, Vt2, 4096, 2048, 1024);
  hipLaunchKernelGGL((gemm_bt<u16, 0>), dim3(8, 16), dim3(256), 0, stream,
                     inbf, WqT, b_q, qq, (u16*)nullptr, 2048, 1024, 1024);
  hipLaunchKernelGGL((gemm_bt<u16, 2>), dim3(8, 8), dim3(256), 0, stream,
                     pebf, WposT, b_pos, Rt, (u16*)nullptr, 1024, 1024, 1024);
  // --- split-j fused attention + combine
  hipLaunchKernelGGL(flash_xl, dim3(16, 4, 16), dim3(256), 0, stream,
                     qq, Kt2, Vt2, Rt, u, v, po, pm, pl);
  hipLaunchKernelGGL(combine, dim3(8192), dim3(256), 0, stream, po, pm, pl, av);
  // --- output projection
  hipLaunchKernelGGL((gemm_bt<float, 0>), dim3(8, 16), dim3(256), 0, stream,
                     av, WprojT, b_proj, out, (u16*)nullptr, 2048, 1024, 1024);
}